// Round 6
// baseline (418.995 us; speedup 1.0000x reference)
//
#include <hip/hip_runtime.h>
#include <hip/hip_fp16.h>
#include <cstdint>

// ---------- types ----------
typedef _Float16 half8 __attribute__((ext_vector_type(8)));
typedef _Float16 half4 __attribute__((ext_vector_type(4)));
typedef float floatx4 __attribute__((ext_vector_type(4)));

#define S_TOT 8192
#define H_DIM 1152
#define NHEAD 16
#define HD 72
#define QSTR 96      // Q row stride (els), zeros in 72..95
#define KSTR 104     // K row stride (els), zeros in 72..103
#define PSTR 76      // P LDS row stride (bank-spread: 38 dw == 6 mod 32)
#define VSTR 76      // V^T tile row stride
#define VT_TILE 6080 // 80*76 els per (n,h,kb) V^T tile
#define NSEG 8
#define SEGL 1024
// 72^-0.5 * log2(e): exp2-based softmax, scale folded into Q
#define QSCALE 0.17002324631230988f

// async global->LDS 16B; LDS side is wave-uniform base + lane*16 (global side per-lane free)
__device__ __forceinline__ void gld_lds16(const void* g, void* l) {
  __builtin_amdgcn_global_load_lds((const __attribute__((address_space(1))) void*)g,
                                   (__attribute__((address_space(3))) void*)l, 16, 0, 0);
}

// ---------- elementwise cast fp32 -> f16 ----------
__global__ void cast_f32_f16(const float* __restrict__ in, _Float16* __restrict__ out, int n) {
  int i = (blockIdx.x * 256 + threadIdx.x) * 4;
  if (i < n) {
    float4 v = *(const float4*)(in + i);
    half4 o = { (_Float16)v.x, (_Float16)v.y, (_Float16)v.z, (_Float16)v.w };
    *(half4*)(out + i) = o;
  }
}

// ---------- transpose + cast: W[R][C] fp32 -> Wt[C][R] f16 ----------
__global__ void transpose_cast(const float* __restrict__ W, _Float16* __restrict__ Wt,
                               int R, int C) {
  __shared__ float tile[32][33];
  int tx = threadIdx.x, ty = threadIdx.y;          // (32,8)
  int bx = blockIdx.x, by = blockIdx.y;
#pragma unroll
  for (int i = 0; i < 4; ++i)
    tile[ty + i * 8][tx] = W[(size_t)(by * 32 + ty + i * 8) * C + bx * 32 + tx];
  __syncthreads();
#pragma unroll
  for (int i = 0; i < 4; ++i)
    Wt[(size_t)(bx * 32 + ty + i * 8) * R + by * 32 + tx] = (_Float16)tile[tx][ty + i * 8];
}

// ---------- 256x256 GEMM, BK=32, 4-slot LDS + STATIC register double-buffer ----------
// FROZEN (r4): 5 schedule variants all pin at MfmaUtil ~31% — structure exhausted at HIP level.
// Used for the QKV projection (448 blocks). Out-projection uses 128^2 gemm_bt (wave balance).
template <bool OUT_HALF>
__global__ __launch_bounds__(512, 2) void gemm256(
    const _Float16* __restrict__ A, const _Float16* __restrict__ Bt,
    const float* __restrict__ bias, float* __restrict__ Cf, _Float16* __restrict__ Ch,
    int M, int N, int K, int NT) {
  extern __shared__ half8 smem8[];
  char* smem = (char*)smem8;
  const int tid = threadIdx.x;
  const int lane = tid & 63;
  const int w = tid >> 6;
  const int quad = lane >> 4, l16 = lane & 15;
  const int wm = w >> 2, wn = w & 3;               // 2 x 4 waves

  // XCD mapping: each XCD owns 4 m-tiles x all NT n-tiles (keeps FETCH ~50MB, r2)
  const int orig = blockIdx.x;
  const int xcd = orig & 7, widx = orig >> 3;
  const int mt = xcd * 4 + (widx & 3), nt = widx >> 2;
  const int m0 = mt * 256, n0 = nt * 256;

  // ---- staging geometry: chunk c = i*512+tid -> row=c>>2, cs=c&3, src col-chunk = cs^((row>>1)&3)
  const _Float16* pA[2];
  const _Float16* pB[2];
#pragma unroll
  for (int i = 0; i < 2; ++i) {
    int c = i * 512 + tid;
    int r = c >> 2, cs = c & 3;
    int col = ((cs ^ ((r >> 1) & 3)) << 3);
    pA[i] = A + (size_t)(m0 + r) * K + col;
    int br = n0 + r; if (br >= N) br = N - 1;      // clamp pad rows (outputs masked)
    pB[i] = Bt + (size_t)br * K + col;
  }
  const int st0 = tid * 16, st1 = tid * 16 + 8192;
  // ---- ds_read offsets (swizzled): chunk read at quad ^ ((l16>>1)&3) -> canonical k-chunk
  const int rsl = ((quad ^ ((l16 >> 1) & 3)) << 4);
  const int aoff = (wm * 128 + l16) * 64 + rsl;
  const int boff = 16384 + (wn * 64 + l16) * 64 + rsl;

  half8 afA[8], bfA[4], afB[8], bfB[4];
  floatx4 acc[8][4] = {};

#define STG_A(ds, kcol) { \
  gld_lds16(pA[0] + (kcol), smem + (ds) * 32768 + st0); \
  gld_lds16(pA[1] + (kcol), smem + (ds) * 32768 + st1); }
#define STG_B(ds, kcol) { \
  gld_lds16(pB[0] + (kcol), smem + (ds) * 32768 + 16384 + st0); \
  gld_lds16(pB[1] + (kcol), smem + (ds) * 32768 + 16384 + st1); }
#define LDB4(s, bfx) { \
  _Pragma("unroll") for (int in = 0; in < 4; ++in) \
    bfx[in] = *(const half8*)(smem + (s) * 32768 + boff + in * 1024); }
#define LDA8(s, afx) { \
  _Pragma("unroll") for (int j = 0; j < 8; ++j) \
    afx[j] = *(const half8*)(smem + (s) * 32768 + aoff + j * 1024); }
#define MFMA32(afx, bfx) { \
  __builtin_amdgcn_s_setprio(1); \
  _Pragma("unroll") for (int j = 0; j < 8; ++j) \
  _Pragma("unroll") for (int in = 0; in < 4; ++in) \
    acc[j][in] = \
      __builtin_amdgcn_mfma_f32_16x16x32_f16(afx[j], bfx[in], acc[j][in], 0, 0, 0); \
  __builtin_amdgcn_s_setprio(0); }
#define BAR() __builtin_amdgcn_s_barrier()
#define SBAR() __builtin_amdgcn_sched_barrier(0)
#define LGKM0() { asm volatile("s_waitcnt lgkmcnt(0)" ::: "memory"); SBAR(); }
#define VMWAIT(t) { \
  if ((t) + 3 < KT)        { asm volatile("s_waitcnt vmcnt(4)" ::: "memory"); } \
  else if ((t) + 3 == KT)  { asm volatile("s_waitcnt vmcnt(0)" ::: "memory"); } }

  // ---- prologue: stage K-tiles 0,1,2; drain tiles 0,1 (vmcnt(4)); preload frags of tile 0 -> A
  STG_A(0, 0);  STG_B(0, 0);
  STG_A(1, 32); STG_B(1, 32);
  STG_A(2, 64); STG_B(2, 64);
  asm volatile("s_waitcnt vmcnt(4)" ::: "memory");
  BAR();
  LDB4(0, bfA); LDA8(0, afA);
  LGKM0();

  const int KT = K >> 5;     // 36 K-tiles (even)
#pragma unroll 1
  for (int u = 0; u < KT; u += 2) {
    // ---- tile t = u: compute from A, prefetch tile u+1 -> B, stage tile u+3
    {
      const int rs = (u + 1) & 3, ws = (u + 3) & 3;
      LDB4(rs, bfB); LDA8(rs, afB);
      if (u + 3 < KT) { STG_A(ws, (u + 3) * 32); STG_B(ws, (u + 3) * 32); }
      SBAR();
      MFMA32(afA, bfA);
      SBAR();
      LGKM0();
      VMWAIT(u);
      BAR();
    }
    // ---- tile t = u+1: compute from B, prefetch tile u+2 -> A, stage tile u+4
    {
      const int rs = (u + 2) & 3, ws = (u + 4) & 3;
      if (u + 2 < KT) { LDB4(rs, bfA); LDA8(rs, afA); }
      if (u + 4 < KT) { STG_A(ws, (u + 4) * 32); STG_B(ws, (u + 4) * 32); }
      SBAR();
      MFMA32(afB, bfB);
      SBAR();
      LGKM0();
      VMWAIT(u + 1);
      if (u + 2 < KT) BAR();
    }
  }
#undef STG_A
#undef STG_B
#undef LDB4
#undef LDA8
#undef MFMA32
#undef BAR
#undef SBAR
#undef LGKM0
#undef VMWAIT

  // ---- epilogue: C write (guard n < N for padded tiles)
#pragma unroll
  for (int im = 0; im < 8; ++im) {
    int m = m0 + wm * 128 + im * 16 + quad * 4;
#pragma unroll
    for (int in = 0; in < 4; ++in) {
      int n = n0 + wn * 64 + in * 16 + l16;
      if (n < N) {
        float b = bias[n];
#pragma unroll
        for (int r = 0; r < 4; ++r) {
          float v = acc[im][in][r] + b;
          if (OUT_HALF) Ch[(size_t)(m + r) * N + n] = (_Float16)v;
          else          Cf[(size_t)(m + r) * N + n] = v;
        }
      }
    }
  }
}

// ---------- 128x128 GEMM (r0 structure) for the out-projection: wave-balanced grid ----------
template <bool OUT_HALF>
__global__ __launch_bounds__(256) void gemm_bt(
    const _Float16* __restrict__ A, const _Float16* __restrict__ Bt,
    const float* __restrict__ bias, float* __restrict__ Cf, _Float16* __restrict__ Ch,
    int M, int N, int K, int NT) {
  __shared__ __align__(16) _Float16 As[128 * 72];   // 18432 B
  __shared__ __align__(16) _Float16 Bs[128 * 72];
  const int tid = threadIdx.x;
  const int lane = tid & 63, w = tid >> 6;
  const int quad = lane >> 4, l16 = lane & 15;
  const int wm = w >> 1, wn = w & 1;
  const int id = blockIdx.x;
  const int j = id & 7, k = id >> 3;
  const int nt_ = k % NT, mt_ = (k / NT) * 8 + j;
  const int m0 = mt_ * 128, n0 = nt_ * 128;

  int rowi[5], cci[5];
#pragma unroll
  for (int i = 0; i < 5; ++i) {
    int c = tid + i * 256;
    int r = c / 9, cc = c - r * 9;
    rowi[i] = r;
    cci[i] = (cc == 8) ? 0 : cc;   // pad chunk: harmless re-read, never consumed
  }

  floatx4 acc[4][4] = {};

  for (int kt = 0; kt < K; kt += 64) {
    __syncthreads();
#pragma unroll
    for (int i = 0; i < 4; ++i) {
      gld_lds16(A + (size_t)(m0 + rowi[i]) * K + kt + cci[i] * 8, (char*)As + (tid + i * 256) * 16);
      gld_lds16(Bt + (size_t)(n0 + rowi[i]) * K + kt + cci[i] * 8, (char*)Bs + (tid + i * 256) * 16);
    }
    if (tid < 128) {
      gld_lds16(A + (size_t)(m0 + rowi[4]) * K + kt + cci[4] * 8, (char*)As + (tid + 1024) * 16);
      gld_lds16(Bt + (size_t)(n0 + rowi[4]) * K + kt + cci[4] * 8, (char*)Bs + (tid + 1024) * 16);
    }
    __syncthreads();
#pragma unroll
    for (int kk = 0; kk < 2; ++kk) {
      half8 af[4], bf[4];
#pragma unroll
      for (int im = 0; im < 4; ++im)
        af[im] = *(const half8*)&As[(wm * 64 + im * 16 + l16) * 72 + kk * 32 + quad * 8];
#pragma unroll
      for (int in = 0; in < 4; ++in)
        bf[in] = *(const half8*)&Bs[(wn * 64 + in * 16 + l16) * 72 + kk * 32 + quad * 8];
#pragma unroll
      for (int im = 0; im < 4; ++im)
#pragma unroll
        for (int in = 0; in < 4; ++in)
          acc[im][in] = __builtin_amdgcn_mfma_f32_16x16x32_f16(af[im], bf[in], acc[im][in], 0, 0, 0);
    }
  }
#pragma unroll
  for (int im = 0; im < 4; ++im) {
    int m = m0 + wm * 64 + im * 16 + quad * 4;
#pragma unroll
    for (int in = 0; in < 4; ++in) {
      int n = n0 + wn * 64 + in * 16 + l16;
      float b = bias[n];
#pragma unroll
      for (int r = 0; r < 4; ++r) {
        float v = acc[im][in][r] + b;
        if (OUT_HALF) Ch[(size_t)(m + r) * N + n] = (_Float16)v;
        else          Cf[(size_t)(m + r) * N + n] = v;
      }
    }
  }
}

// ---------- RoPE Q,K with LDS-coalesced stores (r5, kept) ----------
__global__ __launch_bounds__(256) void rope_scatter(
    const _Float16* __restrict__ QKV,  // [S][3456]
    const float* __restrict__ cosb,    // [S][72]
    const float* __restrict__ sinb,
    _Float16* __restrict__ Qo, _Float16* __restrict__ Ko) {
  __shared__ __align__(16) _Float16 Ls[256 * 120];   // 61440 B (2 blocks/CU)
  const int tid = threadIdx.x;
  const int t0 = blockIdx.x * 256;        // 256 rows/block, same (n,h) per block (l-aligned)
  const int t = t0 + tid;                 // output row = (n*16+h)*1024 + l
  const int l = t & 1023, h = (t >> 10) & 15, n = t >> 14;
  const int s = n * SEGL + l;
  const _Float16* q = QKV + (size_t)s * 3456 + h * HD;
  const _Float16* k = q + H_DIM;
  const float* cs = cosb + (size_t)s * HD;
  const float* sn = sinb + (size_t)s * HD;
  half8 z = {};
  // ---- Q: compute -> LDS (stride 104) -> coalesced flush (96 els/row)
  {
    _Float16 qr[72], qv[72];
#pragma unroll
    for (int i = 0; i < 9; ++i) *(half8*)&qr[8 * i] = *(const half8*)(q + 8 * i);
#pragma unroll
    for (int d = 0; d < 36; ++d) {
      float c0 = cs[d], s0 = sn[d], c1 = cs[d + 36], s1 = sn[d + 36];
      float a = (float)qr[d], b = (float)qr[d + 36];
      qv[d]      = (_Float16)((a * c0 - b * s0) * QSCALE);
      qv[d + 36] = (_Float16)((b * c1 + a * s1) * QSCALE);
    }
#pragma unroll
    for (int i = 0; i < 9; ++i) *(half8*)&Ls[tid * 104 + 8 * i] = *(half8*)&qv[8 * i];
#pragma unroll
    for (int i = 9; i < 12; ++i) *(half8*)&Ls[tid * 104 + 8 * i] = z;
  }
  __syncthreads();
  {
    _Float16* dst = Qo + (size_t)t0 * QSTR;
#pragma unroll
    for (int it = 0; it < 12; ++it) {          // 256 rows x 12 chunks = 3072
      int j = tid + it * 256;
      int row = j / 12, c = j - row * 12;
      *(half8*)(dst + (size_t)j * 8) = *(const half8*)&Ls[row * 104 + c * 8];
    }
  }
  __syncthreads();
  // ---- K: compute -> LDS (stride 120) -> coalesced flush (104 els/row)
  {
    _Float16 kr[72], kv[72];
#pragma unroll
    for (int i = 0; i < 9; ++i) *(half8*)&kr[8 * i] = *(const half8*)(k + 8 * i);
#pragma unroll
    for (int d = 0; d < 36; ++d) {
      float c0 = cs[d], s0 = sn[d], c1 = cs[d + 36], s1 = sn[d + 36];
      float a = (float)kr[d], b = (float)kr[d + 36];
      kv[d]      = (_Float16)(a * c0 - b * s0);
      kv[d + 36] = (_Float16)(b * c1 + a * s1);
    }
#pragma unroll
    for (int i = 0; i < 9; ++i) *(half8*)&Ls[tid * 120 + 8 * i] = *(half8*)&kv[8 * i];
#pragma unroll
    for (int i = 9; i < 13; ++i) *(half8*)&Ls[tid * 120 + 8 * i] = z;  // full 104: no holes
  }
  __syncthreads();
  {
    _Float16* dst = Ko + (size_t)t0 * KSTR;
#pragma unroll
    for (int it = 0; it < 13; ++it) {          // 256 rows x 13 chunks = 3328
      int j = tid + it * 256;
      int row = j / 13, c = j - row * 13;
      *(half8*)(dst + (size_t)j * 8) = *(const half8*)&Ls[row * 120 + c * 8];
    }
  }
}

// ---------- V pre-transpose -> Vt tiles [n,h,kb][d:80][76]; row d=72 = ones (l_s trick) ----------
__global__ __launch_bounds__(256) void transpose_v(const _Float16* __restrict__ QKV,
                                                   _Float16* __restrict__ Vt) {
  __shared__ __align__(16) _Float16 Vs[64 * 88];   // [key][d pad 88]
  const int tid = threadIdx.x;
  const int kb = blockIdx.x, h = blockIdx.y, n = blockIdx.z;
  const int s0 = n * SEGL + kb * 64;
  const _Float16* src = QKV + (size_t)s0 * 3456 + 2 * H_DIM + h * HD;
  for (int idx = tid; idx < 576; idx += 256) {
    int key = idx / 9, c = idx - key * 9;
    *(half8*)&Vs[key * 88 + c * 8] = *(const half8*)(src + (size_t)key * 3456 + c * 8);
  }
  __syncthreads();
  _Float16* dst = Vt + (((size_t)(n * NHEAD + h)) * 16 + kb) * VT_TILE;
  for (int idx = tid; idx < 800; idx += 256) {  // 80 rows x 10 chunks
    int d = idx / 10, c = idx - d * 10;
    if (c < 8) {            // key cols 0..63
      half8 v = {};
      if (d < HD) {
#pragma unroll
        for (int j = 0; j < 8; ++j) v[j] = Vs[(c * 8 + j) * 88 + d];
      } else if (d == HD) { // ones row: PV MFMA accumulates sum(P) here
#pragma unroll
        for (int j = 0; j < 8; ++j) v[j] = (_Float16)1.0f;
      }
      *(half8*)(dst + d * VSTR + c * 8) = v;
    } else if (c == 8) {
      *(half8*)(dst + d * VSTR + 64) = half8{};  // pad cols 64..71
    } else {
      *(half4*)(dst + d * VSTR + 72) = half4{};  // pad cols 72..75
    }
  }
}

// ---------- flash attention (S^T), 32 q/wave, 128 q/block, grid 1024 ----------
// Double-buffered K/V staging, ONE barrier per K-tile (stage-after-barrier: tile kb+1's
// loads land under compute of tile kb; the next barrier's drain then costs ~0).
// Staging is exec-uniform (7 gld/thread, per-lane clamped global addr) so the drain
// semantics are wave-uniform and there are no OOB reads at segment ends.
// LDS 67072 B dynamic: 2 slots x (K 16384 + V 12288) + Ps 9728 -> 2 blocks/CU.
__global__ __launch_bounds__(256, 2) void attn_kernel(
    const _Float16* __restrict__ Qb, const _Float16* __restrict__ Kb,
    const _Float16* __restrict__ Vtb, _Float16* __restrict__ Ctx) {
  extern __shared__ __align__(16) char asmem[];
  const int tid = threadIdx.x;
  const int lane = tid & 63, w = tid >> 6;
  const int quad = lane >> 4, l16 = lane & 15;
  // swizzle: 8 qb-blocks of one (h,n) share id mod 8 -> same XCD L2
  const int id = blockIdx.x;
  const int hn = id & 127, qb = id >> 7;
  const int h = hn >> 3, n = hn & 7;
  const size_t hseg = (size_t)(n * NHEAD + h);
  const _Float16* Qg = Qb + hseg * SEGL * QSTR;
  const _Float16* Kg = Kb + hseg * SEGL * KSTR;
  const _Float16* Vg = Vtb + hseg * 16 * VT_TILE;
  _Float16* Ps = (_Float16*)(asmem + 57344);

  // 7 uniform gld_lds per thread: K 4 chunks (last addr-clamped), V 3 chunks (last clamped)
  auto STAGE = [&](int kb2, int slot) {
    const char* kbase = (const char*)(Kg + (size_t)kb2 * 64 * KSTR);
    char* kdst = asmem + slot * 28672;
    gld_lds16(kbase + tid * 16,         kdst + tid * 16);
    gld_lds16(kbase + tid * 16 + 4096,  kdst + tid * 16 + 4096);
    gld_lds16(kbase + tid * 16 + 8192,  kdst + tid * 16 + 8192);
    int ko = tid * 16 + 12288; if (ko > 13296) ko = 13296;   // tile = 13312 B
    gld_lds16(kbase + ko,               kdst + tid * 16 + 12288);
    const char* vbase = (const char*)(Vg + (size_t)kb2 * VT_TILE);
    char* vdst = kdst + 16384;
    gld_lds16(vbase + tid * 16,         vdst + tid * 16);
    gld_lds16(vbase + tid * 16 + 4096,  vdst + tid * 16 + 4096);
    int vo = tid * 16 + 8192; if (vo > 12144) vo = 12144;    // tile = 12160 B
    gld_lds16(vbase + vo,               vdst + tid * 16 + 8192);
  };

  half8 qf[2][3];
#pragma unroll
  for (int qg = 0; qg < 2; ++qg) {
    int row = qb * 128 + w * 32 + qg * 16 + l16;
#pragma unroll
    for (int kc = 0; kc < 3; ++kc)
      qf[qg][kc] = *(const half8*)(Qg + (size_t)row * QSTR + kc * 32 + quad * 8);
  }
  floatx4 o_acc[2][5] = {};   // O^T[d = t*16+quad*4+r][q]; t=4,quad=2,r=0 carries sum(P)

  STAGE(0, 0);
  for (int kb = 0; kb < SEGL / 64; ++kb) {
    __syncthreads();   // drain: tile kb's loads complete everywhere; prev compute done
    if (kb < SEGL / 64 - 1) STAGE(kb + 1, (kb + 1) & 1);   // lands under this compute
    const _Float16* Kt = (const _Float16*)(asmem + (kb & 1) * 28672);
    const _Float16* Vt = (const _Float16*)(asmem + (kb & 1) * 28672 + 16384);
    // S^T = K·Q^T (K-frags shared across both q-groups)
    floatx4 sa[2][4] = {};
    __builtin_amdgcn_s_setprio(1);
#pragma unroll
    for (int nt = 0; nt < 4; ++nt) {
      half8 kf[3];
#pragma unroll
      for (int kc = 0; kc < 3; ++kc)
        kf[kc] = *(const half8*)&Kt[(nt * 16 + l16) * KSTR + kc * 32 + quad * 8];
#pragma unroll
      for (int qg = 0; qg < 2; ++qg)
#pragma unroll
        for (int kc = 0; kc < 3; ++kc)
          sa[qg][nt] = __builtin_amdgcn_mfma_f32_16x16x32_f16(kf[kc], qf[qg][kc], sa[qg][nt], 0, 0, 0);
    }
    __builtin_amdgcn_s_setprio(0);
    // p = exp2(s), no max subtraction; no explicit sum (ones-row handles it)
#pragma unroll
    for (int qg = 0; qg < 2; ++qg)
#pragma unroll
      for (int nt = 0; nt < 4; ++nt)
#pragma unroll
        for (int r = 0; r < 4; ++r)
          sa[qg][nt][r] = exp2f(sa[qg][nt][r]);
    // V-frags once per tile, reused across both q-groups
    half8 vf[2][5];
#pragma unroll
    for (int kc2 = 0; kc2 < 2; ++kc2)
#pragma unroll
      for (int t = 0; t < 5; ++t)
        vf[kc2][t] = *(const half8*)&Vt[(t * 16 + l16) * VSTR + kc2 * 32 + quad * 8];
    // per q-group: P -> LDS (wave-private 16 rows, reused across qg; in-order DS = safe)
#pragma unroll
    for (int qg = 0; qg < 2; ++qg) {
      int prow = (w * 16 + l16) * PSTR;
#pragma unroll
      for (int nt = 0; nt < 4; ++nt) {
        half4 ph = { (_Float16)sa[qg][nt][0], (_Float16)sa[qg][nt][1],
                     (_Float16)sa[qg][nt][2], (_Float16)sa[qg][nt][3] };
        *(half4*)&Ps[prow + nt * 16 + quad * 4] = ph;
      }
      __builtin_amdgcn_s_setprio(1);
#pragma unroll
      for (int kc2 = 0; kc2 < 2; ++kc2) {
        half8 pb = *(const half8*)&Ps[(w * 16 + l16) * PSTR + kc2 * 32 + quad * 8];
#pragma unroll
        for (int t = 0; t < 5; ++t)
          o_acc[qg][t] = __builtin_amdgcn_mfma_f32_16x16x32_f16(vf[kc2][t], pb, o_acc[qg][t], 0, 0, 0);
      }
      __builtin_amdgcn_s_setprio(0);
    }
  }
  // epilogue: l = sum(P) lives at t=4, quad=2, r=0 -> broadcast from lane 32+l16
#pragma unroll
  for (int qg = 0; qg < 2; ++qg) {
    float lsum = __shfl(o_acc[qg][4][0], 32 + l16, 64);
    float rl = 1.0f / lsum;
    size_t s2 = (size_t)n * SEGL + qb * 128 + w * 32 + qg * 16 + l16;
#pragma unroll
    for (int t = 0; t < 5; ++t) {
      int d0 = t * 16 + quad * 4;
      if (d0 < HD) {
        half4 hv = { (_Float16)(o_acc[qg][t][0] * rl), (_Float16)(o_acc[qg][t][1] * rl),
                     (_Float16)(o_acc[qg][t][2] * rl), (_Float16)(o_acc[qg][t][3] * rl) };
        *(half4*)&Ctx[s2 * H_DIM + h * HD + d0] = hv;
      }
    }
  }
}

extern "C" void kernel_launch(void* const* d_in, const int* in_sizes, int n_in,
                              void* d_out, int out_size, void* d_ws, size_t ws_size,
                              hipStream_t stream) {
  const float* X    = (const float*)d_in[0];
  const float* cosb = (const float*)d_in[1];
  const float* sinb = (const float*)d_in[2];
  const float* Wqkv = (const float*)d_in[3];
  const float* bqkv = (const float*)d_in[4];
  const float* Wout = (const float*)d_in[5];
  const float* bout = (const float*)d_in[6];
  float* out = (float*)d_out;
  char* ws = (char*)d_ws;

  _Float16* Xb   = (_Float16*)(ws);              // 18,874,368 (reused as Ctx)
  _Float16* Wqt  = (_Float16*)(ws + 18874368);   //  7,962,624
  _Float16* Wot  = (_Float16*)(ws + 26836992);   //  2,654,208
  _Float16* QKVb = (_Float16*)(ws + 29491200);   // 56,623,104
  _Float16* Qb   = (_Float16*)(ws + 86114304);   // 25,165,824
  _Float16* Kb   = (_Float16*)(ws + 111280128);  // 27,262,976
  _Float16* Vtb  = (_Float16*)(ws + 138543104);  // 24,903,680
  _Float16* Ctx  = Xb;

  static bool attr_done = false;
  if (!attr_done) {
    hipFuncSetAttribute(reinterpret_cast<const void*>(gemm256<true>),
                        hipFuncAttributeMaxDynamicSharedMemorySize, 131072);
    hipFuncSetAttribute(reinterpret_cast<const void*>(attn_kernel),
                        hipFuncAttributeMaxDynamicSharedMemorySize, 67072);
    attr_done = true;
  }

  cast_f32_f16<<<9216, 256, 0, stream>>>(X, Xb, S_TOT * H_DIM);
  transpose_cast<<<dim3(108, 36), dim3(32, 8), 0, stream>>>(Wqkv, Wqt, H_DIM, 3 * H_DIM);
  transpose_cast<<<dim3(36, 36), dim3(32, 8), 0, stream>>>(Wout, Wot, H_DIM, H_DIM);
  // QKV: M=8192, N=3456 (14 tiles, last masked), K=1152 -> 448 wg
  gemm256<true><<<448, 512, 131072, stream>>>(Xb, Wqt, bqkv, nullptr, QKVb,
                                              S_TOT, 3 * H_DIM, H_DIM, 14);
  rope_scatter<<<512, 256, 0, stream>>>(QKVb, cosb, sinb, Qb, Kb);
  transpose_v<<<dim3(16, 16, 8), 256, 0, stream>>>(QKVb, Vtb);
  attn_kernel<<<1024, 256, 67072, stream>>>(Qb, Kb, Vtb, Ctx);
  // out: M=8192, N=1152, K=1152 -> 128^2 tiles, 576 wg (wave-balanced, 2.25 rounds)
  gemm_bt<false><<<576, 256, 0, stream>>>(Ctx, Wot, bout, out, nullptr,
                                          S_TOT, H_DIM, H_DIM, 9);
}

// Round 7
// 383.205 us; speedup vs baseline: 1.0934x; 1.0934x over previous
//
#include <hip/hip_runtime.h>
#include <hip/hip_fp16.h>
#include <cstdint>

// ---------- types ----------
typedef _Float16 half8 __attribute__((ext_vector_type(8)));
typedef _Float16 half4 __attribute__((ext_vector_type(4)));
typedef float floatx4 __attribute__((ext_vector_type(4)));

#define S_TOT 8192
#define H_DIM 1152
#define NHEAD 16
#define HD 72
#define QSTR 96      // Q row stride (els), zeros in 72..95
#define KSTR 104     // K row stride (els), zeros in 72..103
#define PSTR 76      // P LDS row stride (bank-spread: 38 dw == 6 mod 32)
#define VSTR 76      // V^T tile row stride
#define VT_TILE 6080 // 80*76 els per (n,h,kb) V^T tile
#define NSEG 8
#define SEGL 1024
// 72^-0.5 * log2(e): exp2-based softmax, scale folded into Q
#define QSCALE 0.17002324631230988f

// async global->LDS 16B; LDS side is wave-uniform base + lane*16 (global side per-lane free)
__device__ __forceinline__ void gld_lds16(const void* g, void* l) {
  __builtin_amdgcn_global_load_lds((const __attribute__((address_space(1))) void*)g,
                                   (__attribute__((address_space(3))) void*)l, 16, 0, 0);
}

// ---------- elementwise cast fp32 -> f16 ----------
__global__ void cast_f32_f16(const float* __restrict__ in, _Float16* __restrict__ out, int n) {
  int i = (blockIdx.x * 256 + threadIdx.x) * 4;
  if (i < n) {
    float4 v = *(const float4*)(in + i);
    half4 o = { (_Float16)v.x, (_Float16)v.y, (_Float16)v.z, (_Float16)v.w };
    *(half4*)(out + i) = o;
  }
}

// ---------- transpose + cast: W[R][C] fp32 -> Wt[C][R] f16 ----------
__global__ void transpose_cast(const float* __restrict__ W, _Float16* __restrict__ Wt,
                               int R, int C) {
  __shared__ float tile[32][33];
  int tx = threadIdx.x, ty = threadIdx.y;          // (32,8)
  int bx = blockIdx.x, by = blockIdx.y;
#pragma unroll
  for (int i = 0; i < 4; ++i)
    tile[ty + i * 8][tx] = W[(size_t)(by * 32 + ty + i * 8) * C + bx * 32 + tx];
  __syncthreads();
#pragma unroll
  for (int i = 0; i < 4; ++i)
    Wt[(size_t)(bx * 32 + ty + i * 8) * R + by * 32 + tx] = (_Float16)tile[tx][ty + i * 8];
}

// ---------- 256x256 GEMM, BK=32, 4-slot LDS + STATIC register double-buffer ----------
// FROZEN (r4): 5 schedule variants all pin at MfmaUtil ~31% — structure exhausted at HIP level.
template <bool OUT_HALF>
__global__ __launch_bounds__(512, 2) void gemm256(
    const _Float16* __restrict__ A, const _Float16* __restrict__ Bt,
    const float* __restrict__ bias, float* __restrict__ Cf, _Float16* __restrict__ Ch,
    int M, int N, int K, int NT) {
  extern __shared__ half8 smem8[];
  char* smem = (char*)smem8;
  const int tid = threadIdx.x;
  const int lane = tid & 63;
  const int w = tid >> 6;
  const int quad = lane >> 4, l16 = lane & 15;
  const int wm = w >> 2, wn = w & 3;               // 2 x 4 waves

  // XCD mapping: each XCD owns 4 m-tiles x all NT n-tiles (keeps FETCH ~50MB, r2)
  const int orig = blockIdx.x;
  const int xcd = orig & 7, widx = orig >> 3;
  const int mt = xcd * 4 + (widx & 3), nt = widx >> 2;
  const int m0 = mt * 256, n0 = nt * 256;

  // ---- staging geometry: chunk c = i*512+tid -> row=c>>2, cs=c&3, src col-chunk = cs^((row>>1)&3)
  const _Float16* pA[2];
  const _Float16* pB[2];
#pragma unroll
  for (int i = 0; i < 2; ++i) {
    int c = i * 512 + tid;
    int r = c >> 2, cs = c & 3;
    int col = ((cs ^ ((r >> 1) & 3)) << 3);
    pA[i] = A + (size_t)(m0 + r) * K + col;
    int br = n0 + r; if (br >= N) br = N - 1;      // clamp pad rows (outputs masked)
    pB[i] = Bt + (size_t)br * K + col;
  }
  const int st0 = tid * 16, st1 = tid * 16 + 8192;
  // ---- ds_read offsets (swizzled): chunk read at quad ^ ((l16>>1)&3) -> canonical k-chunk
  const int rsl = ((quad ^ ((l16 >> 1) & 3)) << 4);
  const int aoff = (wm * 128 + l16) * 64 + rsl;
  const int boff = 16384 + (wn * 64 + l16) * 64 + rsl;

  half8 afA[8], bfA[4], afB[8], bfB[4];
  floatx4 acc[8][4] = {};

#define STG_A(ds, kcol) { \
  gld_lds16(pA[0] + (kcol), smem + (ds) * 32768 + st0); \
  gld_lds16(pA[1] + (kcol), smem + (ds) * 32768 + st1); }
#define STG_B(ds, kcol) { \
  gld_lds16(pB[0] + (kcol), smem + (ds) * 32768 + 16384 + st0); \
  gld_lds16(pB[1] + (kcol), smem + (ds) * 32768 + 16384 + st1); }
#define LDB4(s, bfx) { \
  _Pragma("unroll") for (int in = 0; in < 4; ++in) \
    bfx[in] = *(const half8*)(smem + (s) * 32768 + boff + in * 1024); }
#define LDA8(s, afx) { \
  _Pragma("unroll") for (int j = 0; j < 8; ++j) \
    afx[j] = *(const half8*)(smem + (s) * 32768 + aoff + j * 1024); }
#define MFMA32(afx, bfx) { \
  __builtin_amdgcn_s_setprio(1); \
  _Pragma("unroll") for (int j = 0; j < 8; ++j) \
  _Pragma("unroll") for (int in = 0; in < 4; ++in) \
    acc[j][in] = \
      __builtin_amdgcn_mfma_f32_16x16x32_f16(afx[j], bfx[in], acc[j][in], 0, 0, 0); \
  __builtin_amdgcn_s_setprio(0); }
#define BAR() __builtin_amdgcn_s_barrier()
#define SBAR() __builtin_amdgcn_sched_barrier(0)
#define LGKM0() { asm volatile("s_waitcnt lgkmcnt(0)" ::: "memory"); SBAR(); }
#define VMWAIT(t) { \
  if ((t) + 3 < KT)        { asm volatile("s_waitcnt vmcnt(4)" ::: "memory"); } \
  else if ((t) + 3 == KT)  { asm volatile("s_waitcnt vmcnt(0)" ::: "memory"); } }

  // ---- prologue: stage K-tiles 0,1,2; drain tiles 0,1 (vmcnt(4)); preload frags of tile 0 -> A
  STG_A(0, 0);  STG_B(0, 0);
  STG_A(1, 32); STG_B(1, 32);
  STG_A(2, 64); STG_B(2, 64);
  asm volatile("s_waitcnt vmcnt(4)" ::: "memory");
  BAR();
  LDB4(0, bfA); LDA8(0, afA);
  LGKM0();

  const int KT = K >> 5;     // 36 K-tiles (even)
#pragma unroll 1
  for (int u = 0; u < KT; u += 2) {
    // ---- tile t = u: compute from A, prefetch tile u+1 -> B, stage tile u+3
    {
      const int rs = (u + 1) & 3, ws = (u + 3) & 3;
      LDB4(rs, bfB); LDA8(rs, afB);
      if (u + 3 < KT) { STG_A(ws, (u + 3) * 32); STG_B(ws, (u + 3) * 32); }
      SBAR();
      MFMA32(afA, bfA);
      SBAR();
      LGKM0();
      VMWAIT(u);
      BAR();
    }
    // ---- tile t = u+1: compute from B, prefetch tile u+2 -> A, stage tile u+4
    {
      const int rs = (u + 2) & 3, ws = (u + 4) & 3;
      if (u + 2 < KT) { LDB4(rs, bfA); LDA8(rs, afA); }
      if (u + 4 < KT) { STG_A(ws, (u + 4) * 32); STG_B(ws, (u + 4) * 32); }
      SBAR();
      MFMA32(afB, bfB);
      SBAR();
      LGKM0();
      VMWAIT(u + 1);
      if (u + 2 < KT) BAR();
    }
  }
#undef STG_A
#undef STG_B
#undef LDB4
#undef LDA8
#undef MFMA32
#undef BAR
#undef SBAR
#undef LGKM0
#undef VMWAIT

  // ---- epilogue: C write (guard n < N for padded tiles)
#pragma unroll
  for (int im = 0; im < 8; ++im) {
    int m = m0 + wm * 128 + im * 16 + quad * 4;
#pragma unroll
    for (int in = 0; in < 4; ++in) {
      int n = n0 + wn * 64 + in * 16 + l16;
      if (n < N) {
        float b = bias[n];
#pragma unroll
        for (int r = 0; r < 4; ++r) {
          float v = acc[im][in][r] + b;
          if (OUT_HALF) Ch[(size_t)(m + r) * N + n] = (_Float16)v;
          else          Cf[(size_t)(m + r) * N + n] = v;
        }
      }
    }
  }
}

// ---------- RoPE Q,K with LDS-coalesced stores (r5, kept) ----------
__global__ __launch_bounds__(256) void rope_scatter(
    const _Float16* __restrict__ QKV,  // [S][3456]
    const float* __restrict__ cosb,    // [S][72]
    const float* __restrict__ sinb,
    _Float16* __restrict__ Qo, _Float16* __restrict__ Ko) {
  __shared__ __align__(16) _Float16 Ls[256 * 120];   // 61440 B (2 blocks/CU)
  const int tid = threadIdx.x;
  const int t0 = blockIdx.x * 256;        // 256 rows/block, same (n,h) per block (l-aligned)
  const int t = t0 + tid;                 // output row = (n*16+h)*1024 + l
  const int l = t & 1023, h = (t >> 10) & 15, n = t >> 14;
  const int s = n * SEGL + l;
  const _Float16* q = QKV + (size_t)s * 3456 + h * HD;
  const _Float16* k = q + H_DIM;
  const float* cs = cosb + (size_t)s * HD;
  const float* sn = sinb + (size_t)s * HD;
  half8 z = {};
  // ---- Q: compute -> LDS (stride 104) -> coalesced flush (96 els/row)
  {
    _Float16 qr[72], qv[72];
#pragma unroll
    for (int i = 0; i < 9; ++i) *(half8*)&qr[8 * i] = *(const half8*)(q + 8 * i);
#pragma unroll
    for (int d = 0; d < 36; ++d) {
      float c0 = cs[d], s0 = sn[d], c1 = cs[d + 36], s1 = sn[d + 36];
      float a = (float)qr[d], b = (float)qr[d + 36];
      qv[d]      = (_Float16)((a * c0 - b * s0) * QSCALE);
      qv[d + 36] = (_Float16)((b * c1 + a * s1) * QSCALE);
    }
#pragma unroll
    for (int i = 0; i < 9; ++i) *(half8*)&Ls[tid * 104 + 8 * i] = *(half8*)&qv[8 * i];
#pragma unroll
    for (int i = 9; i < 12; ++i) *(half8*)&Ls[tid * 104 + 8 * i] = z;
  }
  __syncthreads();
  {
    _Float16* dst = Qo + (size_t)t0 * QSTR;
#pragma unroll
    for (int it = 0; it < 12; ++it) {          // 256 rows x 12 chunks = 3072
      int j = tid + it * 256;
      int row = j / 12, c = j - row * 12;
      *(half8*)(dst + (size_t)j * 8) = *(const half8*)&Ls[row * 104 + c * 8];
    }
  }
  __syncthreads();
  // ---- K: compute -> LDS (stride 120) -> coalesced flush (104 els/row)
  {
    _Float16 kr[72], kv[72];
#pragma unroll
    for (int i = 0; i < 9; ++i) *(half8*)&kr[8 * i] = *(const half8*)(k + 8 * i);
#pragma unroll
    for (int d = 0; d < 36; ++d) {
      float c0 = cs[d], s0 = sn[d], c1 = cs[d + 36], s1 = sn[d + 36];
      float a = (float)kr[d], b = (float)kr[d + 36];
      kv[d]      = (_Float16)(a * c0 - b * s0);
      kv[d + 36] = (_Float16)(b * c1 + a * s1);
    }
#pragma unroll
    for (int i = 0; i < 9; ++i) *(half8*)&Ls[tid * 120 + 8 * i] = *(half8*)&kv[8 * i];
#pragma unroll
    for (int i = 9; i < 13; ++i) *(half8*)&Ls[tid * 120 + 8 * i] = z;  // full 104: no holes
  }
  __syncthreads();
  {
    _Float16* dst = Ko + (size_t)t0 * KSTR;
#pragma unroll
    for (int it = 0; it < 13; ++it) {          // 256 rows x 13 chunks = 3328
      int j = tid + it * 256;
      int row = j / 13, c = j - row * 13;
      *(half8*)(dst + (size_t)j * 8) = *(const half8*)&Ls[row * 120 + c * 8];
    }
  }
}

// ---------- V pre-transpose -> Vt tiles [n,h,kb][d:80][76]; row d=72 = ones (l_s trick) ----------
__global__ __launch_bounds__(256) void transpose_v(const _Float16* __restrict__ QKV,
                                                   _Float16* __restrict__ Vt) {
  __shared__ __align__(16) _Float16 Vs[64 * 88];   // [key][d pad 88]
  const int tid = threadIdx.x;
  const int kb = blockIdx.x, h = blockIdx.y, n = blockIdx.z;
  const int s0 = n * SEGL + kb * 64;
  const _Float16* src = QKV + (size_t)s0 * 3456 + 2 * H_DIM + h * HD;
  for (int idx = tid; idx < 576; idx += 256) {
    int key = idx / 9, c = idx - key * 9;
    *(half8*)&Vs[key * 88 + c * 8] = *(const half8*)(src + (size_t)key * 3456 + c * 8);
  }
  __syncthreads();
  _Float16* dst = Vt + (((size_t)(n * NHEAD + h)) * 16 + kb) * VT_TILE;
  for (int idx = tid; idx < 800; idx += 256) {  // 80 rows x 10 chunks
    int d = idx / 10, c = idx - d * 10;
    if (c < 8) {            // key cols 0..63
      half8 v = {};
      if (d < HD) {
#pragma unroll
        for (int j = 0; j < 8; ++j) v[j] = Vs[(c * 8 + j) * 88 + d];
      } else if (d == HD) { // ones row: PV MFMA accumulates sum(P) here
#pragma unroll
        for (int j = 0; j < 8; ++j) v[j] = (_Float16)1.0f;
      }
      *(half8*)(dst + d * VSTR + c * 8) = v;
    } else if (c == 8) {
      *(half8*)(dst + d * VSTR + 64) = half8{};  // pad cols 64..71
    } else {
      *(half4*)(dst + d * VSTR + 72) = half4{};  // pad cols 72..75
    }
  }
}

// ---------- flash attention (S^T), 32 q/wave, 128 q/block, grid 1024 ----------
// r5 structure restored (attn is latency/TLP-bound: r6's dbuf at 2 blocks/CU cost +62us).
// One lever vs r5: __launch_bounds__(256,4) -> 4 blocks/CU resident (35.2KB x 4 = 140.8KB
// LDS, VGPR 80 <= 128), grid 1024 = exactly one balanced round of 4/CU.
__global__ __launch_bounds__(256, 4) void attn_kernel(
    const _Float16* __restrict__ Qb, const _Float16* __restrict__ Kb,
    const _Float16* __restrict__ Vtb, _Float16* __restrict__ Ctx) {
  __shared__ __align__(16) _Float16 Kt[64 * KSTR];     // 13312 B
  __shared__ __align__(16) _Float16 Vt[80 * VSTR];     // 12160 B
  __shared__ __align__(16) _Float16 Ps[4 * 16 * PSTR]; //  9728 B  (16 q rows per wave)
  const int tid = threadIdx.x;
  const int lane = tid & 63, w = tid >> 6;
  const int quad = lane >> 4, l16 = lane & 15;
  // swizzle: 8 qb-blocks of one (h,n) share id mod 8 -> same XCD L2
  const int id = blockIdx.x;
  const int hn = id & 127, qb = id >> 7;
  const int h = hn >> 3, n = hn & 7;
  const size_t hseg = (size_t)(n * NHEAD + h);
  const _Float16* Qg = Qb + hseg * SEGL * QSTR;
  const _Float16* Kg = Kb + hseg * SEGL * KSTR;
  const _Float16* Vg = Vtb + hseg * 16 * VT_TILE;

  half8 qf[2][3];
#pragma unroll
  for (int qg = 0; qg < 2; ++qg) {
    int row = qb * 128 + w * 32 + qg * 16 + l16;
#pragma unroll
    for (int kc = 0; kc < 3; ++kc)
      qf[qg][kc] = *(const half8*)(Qg + (size_t)row * QSTR + kc * 32 + quad * 8);
  }
  floatx4 o_acc[2][5] = {};   // O^T[d = t*16+quad*4+r][q]; t=4,quad=2,r=0 carries sum(P)

  for (int kb = 0; kb < SEGL / 64; ++kb) {
    __syncthreads();
    // K tile: contiguous 13312 B
    {
      const char* base = (const char*)(Kg + (size_t)kb * 64 * KSTR);
#pragma unroll
      for (int i = 0; i < 3; ++i)
        gld_lds16(base + tid * 16 + i * 4096, (char*)Kt + tid * 16 + i * 4096);
      if (tid < 64)
        gld_lds16(base + 12288 + tid * 16, (char*)Kt + 12288 + tid * 16);
    }
    // V^T tile: contiguous 12160 B
    {
      const char* base = (const char*)(Vg + (size_t)kb * VT_TILE);
#pragma unroll
      for (int i = 0; i < 2; ++i)
        gld_lds16(base + tid * 16 + i * 4096, (char*)Vt + tid * 16 + i * 4096);
      if (tid < 248)
        gld_lds16(base + 8192 + tid * 16, (char*)Vt + 8192 + tid * 16);
    }
    __syncthreads();
    // S^T = K·Q^T (K-frags shared across both q-groups)
    floatx4 sa[2][4] = {};
    __builtin_amdgcn_s_setprio(1);
#pragma unroll
    for (int nt = 0; nt < 4; ++nt) {
      half8 kf[3];
#pragma unroll
      for (int kc = 0; kc < 3; ++kc)
        kf[kc] = *(const half8*)&Kt[(nt * 16 + l16) * KSTR + kc * 32 + quad * 8];
#pragma unroll
      for (int qg = 0; qg < 2; ++qg)
#pragma unroll
        for (int kc = 0; kc < 3; ++kc)
          sa[qg][nt] = __builtin_amdgcn_mfma_f32_16x16x32_f16(kf[kc], qf[qg][kc], sa[qg][nt], 0, 0, 0);
    }
    __builtin_amdgcn_s_setprio(0);
    // p = exp2(s), no max subtraction; no explicit sum (ones-row handles it)
#pragma unroll
    for (int qg = 0; qg < 2; ++qg)
#pragma unroll
      for (int nt = 0; nt < 4; ++nt)
#pragma unroll
        for (int r = 0; r < 4; ++r)
          sa[qg][nt][r] = exp2f(sa[qg][nt][r]);
    // V-frags once per tile, reused across both q-groups
    half8 vf[2][5];
#pragma unroll
    for (int kc2 = 0; kc2 < 2; ++kc2)
#pragma unroll
      for (int t = 0; t < 5; ++t)
        vf[kc2][t] = *(const half8*)&Vt[(t * 16 + l16) * VSTR + kc2 * 32 + quad * 8];
    // per q-group: P -> LDS (wave-private 16 rows, reused across qg; in-order DS = safe)
#pragma unroll
    for (int qg = 0; qg < 2; ++qg) {
      int prow = (w * 16 + l16) * PSTR;
#pragma unroll
      for (int nt = 0; nt < 4; ++nt) {
        half4 ph = { (_Float16)sa[qg][nt][0], (_Float16)sa[qg][nt][1],
                     (_Float16)sa[qg][nt][2], (_Float16)sa[qg][nt][3] };
        *(half4*)&Ps[prow + nt * 16 + quad * 4] = ph;
      }
      __builtin_amdgcn_s_setprio(1);
#pragma unroll
      for (int kc2 = 0; kc2 < 2; ++kc2) {
        half8 pb = *(const half8*)&Ps[(w * 16 + l16) * PSTR + kc2 * 32 + quad * 8];
#pragma unroll
        for (int t = 0; t < 5; ++t)
          o_acc[qg][t] = __builtin_amdgcn_mfma_f32_16x16x32_f16(vf[kc2][t], pb, o_acc[qg][t], 0, 0, 0);
      }
      __builtin_amdgcn_s_setprio(0);
    }
  }
  // epilogue: l = sum(P) lives at t=4, quad=2, r=0 -> broadcast from lane 32+l16
#pragma unroll
  for (int qg = 0; qg < 2; ++qg) {
    float lsum = __shfl(o_acc[qg][4][0], 32 + l16, 64);
    float rl = 1.0f / lsum;
    size_t s2 = (size_t)n * SEGL + qb * 128 + w * 32 + qg * 16 + l16;
#pragma unroll
    for (int t = 0; t < 5; ++t) {
      int d0 = t * 16 + quad * 4;
      if (d0 < HD) {
        half4 hv = { (_Float16)(o_acc[qg][t][0] * rl), (_Float16)(o_acc[qg][t][1] * rl),
                     (_Float16)(o_acc[qg][t][2] * rl), (_Float16)(o_acc[qg][t][3] * rl) };
        *(half4*)&Ctx[s2 * H_DIM + h * HD + d0] = hv;
      }
    }
  }
}

extern "C" void kernel_launch(void* const* d_in, const int* in_sizes, int n_in,
                              void* d_out, int out_size, void* d_ws, size_t ws_size,
                              hipStream_t stream) {
  const float* X    = (const float*)d_in[0];
  const float* cosb = (const float*)d_in[1];
  const float* sinb = (const float*)d_in[2];
  const float* Wqkv = (const float*)d_in[3];
  const float* bqkv = (const float*)d_in[4];
  const float* Wout = (const float*)d_in[5];
  const float* bout = (const float*)d_in[6];
  float* out = (float*)d_out;
  char* ws = (char*)d_ws;

  _Float16* Xb   = (_Float16*)(ws);              // 18,874,368 (reused as Ctx)
  _Float16* Wqt  = (_Float16*)(ws + 18874368);   //  7,962,624
  _Float16* Wot  = (_Float16*)(ws + 26836992);   //  2,654,208
  _Float16* QKVb = (_Float16*)(ws + 29491200);   // 56,623,104
  _Float16* Qb   = (_Float16*)(ws + 86114304);   // 25,165,824
  _Float16* Kb   = (_Float16*)(ws + 111280128);  // 27,262,976
  _Float16* Vtb  = (_Float16*)(ws + 138543104);  // 24,903,680
  _Float16* Ctx  = Xb;

  static bool attr_done = false;
  if (!attr_done) {
    hipFuncSetAttribute(reinterpret_cast<const void*>(gemm256<true>),
                        hipFuncAttributeMaxDynamicSharedMemorySize, 131072);
    hipFuncSetAttribute(reinterpret_cast<const void*>(gemm256<false>),
                        hipFuncAttributeMaxDynamicSharedMemorySize, 131072);
    attr_done = true;
  }

  cast_f32_f16<<<9216, 256, 0, stream>>>(X, Xb, S_TOT * H_DIM);
  transpose_cast<<<dim3(108, 36), dim3(32, 8), 0, stream>>>(Wqkv, Wqt, H_DIM, 3 * H_DIM);
  transpose_cast<<<dim3(36, 36), dim3(32, 8), 0, stream>>>(Wout, Wot, H_DIM, H_DIM);
  // QKV: M=8192, N=3456 (14 tiles, last masked), K=1152 -> 448 wg
  gemm256<true><<<448, 512, 131072, stream>>>(Xb, Wqt, bqkv, nullptr, QKVb,
                                              S_TOT, 3 * H_DIM, H_DIM, 14);
  rope_scatter<<<512, 256, 0, stream>>>(QKVb, cosb, sinb, Qb, Kb);
  transpose_v<<<dim3(16, 16, 8), 256, 0, stream>>>(QKVb, Vtb);
  attn_kernel<<<1024, 256, 0, stream>>>(Qb, Kb, Vtb, Ctx);
  // out: M=8192, N=1152 (5 tiles, last masked), K=1152 -> 160 wg (r5-proven)
  gemm256<false><<<160, 512, 131072, stream>>>(Ctx, Wot, bout, out, nullptr,
                                               S_TOT, H_DIM, H_DIM, 5);
}

// Round 8
// 354.077 us; speedup vs baseline: 1.1833x; 1.0823x over previous
//
#include <hip/hip_runtime.h>
#include <hip/hip_fp16.h>
#include <cstdint>

// ---------- types ----------
typedef _Float16 half8 __attribute__((ext_vector_type(8)));
typedef _Float16 half4 __attribute__((ext_vector_type(4)));
typedef float floatx4 __attribute__((ext_vector_type(4)));

#define S_TOT 8192
#define H_DIM 1152
#define NHEAD 16
#define HD 72
#define QSTR 96      // Q row stride (els), zeros in 72..95
#define KSTR 104     // K row stride (els), zeros in 72..103
#define PSTR 76      // P LDS row stride (bank-spread: 38 dw == 6 mod 32)
#define VSTR 76      // V^T tile row stride
#define VT_TILE 6080 // 80*76 els per (n,h,kb) V^T tile
#define NSEG 8
#define SEGL 1024
// 72^-0.5 * log2(e): exp2-based softmax, scale folded into Q
#define QSCALE 0.17002324631230988f

// async global->LDS 16B; LDS side is wave-uniform base + lane*16 (global side per-lane free)
__device__ __forceinline__ void gld_lds16(const void* g, void* l) {
  __builtin_amdgcn_global_load_lds((const __attribute__((address_space(1))) void*)g,
                                   (__attribute__((address_space(3))) void*)l, 16, 0, 0);
}

// ---------- elementwise cast fp32 -> f16 ----------
__global__ void cast_f32_f16(const float* __restrict__ in, _Float16* __restrict__ out, int n) {
  int i = (blockIdx.x * 256 + threadIdx.x) * 4;
  if (i < n) {
    float4 v = *(const float4*)(in + i);
    half4 o = { (_Float16)v.x, (_Float16)v.y, (_Float16)v.z, (_Float16)v.w };
    *(half4*)(out + i) = o;
  }
}

// ---------- transpose + cast: W[R][C] fp32 -> Wt[C][R] f16 ----------
__global__ void transpose_cast(const float* __restrict__ W, _Float16* __restrict__ Wt,
                               int R, int C) {
  __shared__ float tile[32][33];
  int tx = threadIdx.x, ty = threadIdx.y;          // (32,8)
  int bx = blockIdx.x, by = blockIdx.y;
#pragma unroll
  for (int i = 0; i < 4; ++i)
    tile[ty + i * 8][tx] = W[(size_t)(by * 32 + ty + i * 8) * C + bx * 32 + tx];
  __syncthreads();
#pragma unroll
  for (int i = 0; i < 4; ++i)
    Wt[(size_t)(bx * 32 + ty + i * 8) * R + by * 32 + tx] = (_Float16)tile[tx][ty + i * 8];
}

// ---------- 256x256 GEMM, BK=32, 4-slot LDS + STATIC register double-buffer ----------
// FROZEN (r4): 5 schedule variants all pin at MfmaUtil ~31% — structure exhausted at HIP level.
// Used for QKV projection only (448 wg). Out-projection uses gemm_bt 128^2 (576 wg,
// r6-differential: ~13us faster via wave balance).
template <bool OUT_HALF>
__global__ __launch_bounds__(512, 2) void gemm256(
    const _Float16* __restrict__ A, const _Float16* __restrict__ Bt,
    const float* __restrict__ bias, float* __restrict__ Cf, _Float16* __restrict__ Ch,
    int M, int N, int K, int NT) {
  extern __shared__ half8 smem8[];
  char* smem = (char*)smem8;
  const int tid = threadIdx.x;
  const int lane = tid & 63;
  const int w = tid >> 6;
  const int quad = lane >> 4, l16 = lane & 15;
  const int wm = w >> 2, wn = w & 3;               // 2 x 4 waves

  // XCD mapping: each XCD owns 4 m-tiles x all NT n-tiles (keeps FETCH ~50MB, r2)
  const int orig = blockIdx.x;
  const int xcd = orig & 7, widx = orig >> 3;
  const int mt = xcd * 4 + (widx & 3), nt = widx >> 2;
  const int m0 = mt * 256, n0 = nt * 256;

  // ---- staging geometry: chunk c = i*512+tid -> row=c>>2, cs=c&3, src col-chunk = cs^((row>>1)&3)
  const _Float16* pA[2];
  const _Float16* pB[2];
#pragma unroll
  for (int i = 0; i < 2; ++i) {
    int c = i * 512 + tid;
    int r = c >> 2, cs = c & 3;
    int col = ((cs ^ ((r >> 1) & 3)) << 3);
    pA[i] = A + (size_t)(m0 + r) * K + col;
    int br = n0 + r; if (br >= N) br = N - 1;      // clamp pad rows (outputs masked)
    pB[i] = Bt + (size_t)br * K + col;
  }
  const int st0 = tid * 16, st1 = tid * 16 + 8192;
  // ---- ds_read offsets (swizzled): chunk read at quad ^ ((l16>>1)&3) -> canonical k-chunk
  const int rsl = ((quad ^ ((l16 >> 1) & 3)) << 4);
  const int aoff = (wm * 128 + l16) * 64 + rsl;
  const int boff = 16384 + (wn * 64 + l16) * 64 + rsl;

  half8 afA[8], bfA[4], afB[8], bfB[4];
  floatx4 acc[8][4] = {};

#define STG_A(ds, kcol) { \
  gld_lds16(pA[0] + (kcol), smem + (ds) * 32768 + st0); \
  gld_lds16(pA[1] + (kcol), smem + (ds) * 32768 + st1); }
#define STG_B(ds, kcol) { \
  gld_lds16(pB[0] + (kcol), smem + (ds) * 32768 + 16384 + st0); \
  gld_lds16(pB[1] + (kcol), smem + (ds) * 32768 + 16384 + st1); }
#define LDB4(s, bfx) { \
  _Pragma("unroll") for (int in = 0; in < 4; ++in) \
    bfx[in] = *(const half8*)(smem + (s) * 32768 + boff + in * 1024); }
#define LDA8(s, afx) { \
  _Pragma("unroll") for (int j = 0; j < 8; ++j) \
    afx[j] = *(const half8*)(smem + (s) * 32768 + aoff + j * 1024); }
#define MFMA32(afx, bfx) { \
  __builtin_amdgcn_s_setprio(1); \
  _Pragma("unroll") for (int j = 0; j < 8; ++j) \
  _Pragma("unroll") for (int in = 0; in < 4; ++in) \
    acc[j][in] = \
      __builtin_amdgcn_mfma_f32_16x16x32_f16(afx[j], bfx[in], acc[j][in], 0, 0, 0); \
  __builtin_amdgcn_s_setprio(0); }
#define BAR() __builtin_amdgcn_s_barrier()
#define SBAR() __builtin_amdgcn_sched_barrier(0)
#define LGKM0() { asm volatile("s_waitcnt lgkmcnt(0)" ::: "memory"); SBAR(); }
#define VMWAIT(t) { \
  if ((t) + 3 < KT)        { asm volatile("s_waitcnt vmcnt(4)" ::: "memory"); } \
  else if ((t) + 3 == KT)  { asm volatile("s_waitcnt vmcnt(0)" ::: "memory"); } }

  // ---- prologue: stage K-tiles 0,1,2; drain tiles 0,1 (vmcnt(4)); preload frags of tile 0 -> A
  STG_A(0, 0);  STG_B(0, 0);
  STG_A(1, 32); STG_B(1, 32);
  STG_A(2, 64); STG_B(2, 64);
  asm volatile("s_waitcnt vmcnt(4)" ::: "memory");
  BAR();
  LDB4(0, bfA); LDA8(0, afA);
  LGKM0();

  const int KT = K >> 5;     // 36 K-tiles (even)
#pragma unroll 1
  for (int u = 0; u < KT; u += 2) {
    // ---- tile t = u: compute from A, prefetch tile u+1 -> B, stage tile u+3
    {
      const int rs = (u + 1) & 3, ws = (u + 3) & 3;
      LDB4(rs, bfB); LDA8(rs, afB);
      if (u + 3 < KT) { STG_A(ws, (u + 3) * 32); STG_B(ws, (u + 3) * 32); }
      SBAR();
      MFMA32(afA, bfA);
      SBAR();
      LGKM0();
      VMWAIT(u);
      BAR();
    }
    // ---- tile t = u+1: compute from B, prefetch tile u+2 -> A, stage tile u+4
    {
      const int rs = (u + 2) & 3, ws = (u + 4) & 3;
      if (u + 2 < KT) { LDB4(rs, bfA); LDA8(rs, afA); }
      if (u + 4 < KT) { STG_A(ws, (u + 4) * 32); STG_B(ws, (u + 4) * 32); }
      SBAR();
      MFMA32(afB, bfB);
      SBAR();
      LGKM0();
      VMWAIT(u + 1);
      if (u + 2 < KT) BAR();
    }
  }
#undef STG_A
#undef STG_B
#undef LDB4
#undef LDA8
#undef MFMA32
#undef BAR
#undef SBAR
#undef LGKM0
#undef VMWAIT

  // ---- epilogue: C write (guard n < N for padded tiles)
#pragma unroll
  for (int im = 0; im < 8; ++im) {
    int m = m0 + wm * 128 + im * 16 + quad * 4;
#pragma unroll
    for (int in = 0; in < 4; ++in) {
      int n = n0 + wn * 64 + in * 16 + l16;
      if (n < N) {
        float b = bias[n];
#pragma unroll
        for (int r = 0; r < 4; ++r) {
          float v = acc[im][in][r] + b;
          if (OUT_HALF) Ch[(size_t)(m + r) * N + n] = (_Float16)v;
          else          Cf[(size_t)(m + r) * N + n] = v;
        }
      }
    }
  }
}

// ---------- 128x128 GEMM for the out-projection: wave-balanced grid (r6-proven ~13us win) ----------
template <bool OUT_HALF>
__global__ __launch_bounds__(256) void gemm_bt(
    const _Float16* __restrict__ A, const _Float16* __restrict__ Bt,
    const float* __restrict__ bias, float* __restrict__ Cf, _Float16* __restrict__ Ch,
    int M, int N, int K, int NT) {
  __shared__ __align__(16) _Float16 As[128 * 72];   // 18432 B
  __shared__ __align__(16) _Float16 Bs[128 * 72];
  const int tid = threadIdx.x;
  const int lane = tid & 63, w = tid >> 6;
  const int quad = lane >> 4, l16 = lane & 15;
  const int wm = w >> 1, wn = w & 1;
  const int id = blockIdx.x;
  const int j = id & 7, k = id >> 3;
  const int nt_ = k % NT, mt_ = (k / NT) * 8 + j;
  const int m0 = mt_ * 128, n0 = nt_ * 128;

  int rowi[5], cci[5];
#pragma unroll
  for (int i = 0; i < 5; ++i) {
    int c = tid + i * 256;
    int r = c / 9, cc = c - r * 9;
    rowi[i] = r;
    cci[i] = (cc == 8) ? 0 : cc;   // pad chunk: harmless re-read, never consumed
  }

  floatx4 acc[4][4] = {};

  for (int kt = 0; kt < K; kt += 64) {
    __syncthreads();
#pragma unroll
    for (int i = 0; i < 4; ++i) {
      gld_lds16(A + (size_t)(m0 + rowi[i]) * K + kt + cci[i] * 8, (char*)As + (tid + i * 256) * 16);
      gld_lds16(Bt + (size_t)(n0 + rowi[i]) * K + kt + cci[i] * 8, (char*)Bs + (tid + i * 256) * 16);
    }
    if (tid < 128) {
      gld_lds16(A + (size_t)(m0 + rowi[4]) * K + kt + cci[4] * 8, (char*)As + (tid + 1024) * 16);
      gld_lds16(Bt + (size_t)(n0 + rowi[4]) * K + kt + cci[4] * 8, (char*)Bs + (tid + 1024) * 16);
    }
    __syncthreads();
#pragma unroll
    for (int kk = 0; kk < 2; ++kk) {
      half8 af[4], bf[4];
#pragma unroll
      for (int im = 0; im < 4; ++im)
        af[im] = *(const half8*)&As[(wm * 64 + im * 16 + l16) * 72 + kk * 32 + quad * 8];
#pragma unroll
      for (int in = 0; in < 4; ++in)
        bf[in] = *(const half8*)&Bs[(wn * 64 + in * 16 + l16) * 72 + kk * 32 + quad * 8];
#pragma unroll
      for (int im = 0; im < 4; ++im)
#pragma unroll
        for (int in = 0; in < 4; ++in)
          acc[im][in] = __builtin_amdgcn_mfma_f32_16x16x32_f16(af[im], bf[in], acc[im][in], 0, 0, 0);
    }
  }
#pragma unroll
  for (int im = 0; im < 4; ++im) {
    int m = m0 + wm * 64 + im * 16 + quad * 4;
#pragma unroll
    for (int in = 0; in < 4; ++in) {
      int n = n0 + wn * 64 + in * 16 + l16;
      float b = bias[n];
#pragma unroll
      for (int r = 0; r < 4; ++r) {
        float v = acc[im][in][r] + b;
        if (OUT_HALF) Ch[(size_t)(m + r) * N + n] = (_Float16)v;
        else          Cf[(size_t)(m + r) * N + n] = v;
      }
    }
  }
}

// ---------- RoPE Q,K with LDS-coalesced stores (r5, kept) ----------
__global__ __launch_bounds__(256) void rope_scatter(
    const _Float16* __restrict__ QKV,  // [S][3456]
    const float* __restrict__ cosb,    // [S][72]
    const float* __restrict__ sinb,
    _Float16* __restrict__ Qo, _Float16* __restrict__ Ko) {
  __shared__ __align__(16) _Float16 Ls[256 * 120];   // 61440 B (2 blocks/CU)
  const int tid = threadIdx.x;
  const int t0 = blockIdx.x * 256;        // 256 rows/block, same (n,h) per block (l-aligned)
  const int t = t0 + tid;                 // output row = (n*16+h)*1024 + l
  const int l = t & 1023, h = (t >> 10) & 15, n = t >> 14;
  const int s = n * SEGL + l;
  const _Float16* q = QKV + (size_t)s * 3456 + h * HD;
  const _Float16* k = q + H_DIM;
  const float* cs = cosb + (size_t)s * HD;
  const float* sn = sinb + (size_t)s * HD;
  half8 z = {};
  // ---- Q: compute -> LDS (stride 104) -> coalesced flush (96 els/row)
  {
    _Float16 qr[72], qv[72];
#pragma unroll
    for (int i = 0; i < 9; ++i) *(half8*)&qr[8 * i] = *(const half8*)(q + 8 * i);
#pragma unroll
    for (int d = 0; d < 36; ++d) {
      float c0 = cs[d], s0 = sn[d], c1 = cs[d + 36], s1 = sn[d + 36];
      float a = (float)qr[d], b = (float)qr[d + 36];
      qv[d]      = (_Float16)((a * c0 - b * s0) * QSCALE);
      qv[d + 36] = (_Float16)((b * c1 + a * s1) * QSCALE);
    }
#pragma unroll
    for (int i = 0; i < 9; ++i) *(half8*)&Ls[tid * 104 + 8 * i] = *(half8*)&qv[8 * i];
#pragma unroll
    for (int i = 9; i < 12; ++i) *(half8*)&Ls[tid * 104 + 8 * i] = z;
  }
  __syncthreads();
  {
    _Float16* dst = Qo + (size_t)t0 * QSTR;
#pragma unroll
    for (int it = 0; it < 12; ++it) {          // 256 rows x 12 chunks = 3072
      int j = tid + it * 256;
      int row = j / 12, c = j - row * 12;
      *(half8*)(dst + (size_t)j * 8) = *(const half8*)&Ls[row * 104 + c * 8];
    }
  }
  __syncthreads();
  // ---- K: compute -> LDS (stride 120) -> coalesced flush (104 els/row)
  {
    _Float16 kr[72], kv[72];
#pragma unroll
    for (int i = 0; i < 9; ++i) *(half8*)&kr[8 * i] = *(const half8*)(k + 8 * i);
#pragma unroll
    for (int d = 0; d < 36; ++d) {
      float c0 = cs[d], s0 = sn[d], c1 = cs[d + 36], s1 = sn[d + 36];
      float a = (float)kr[d], b = (float)kr[d + 36];
      kv[d]      = (_Float16)(a * c0 - b * s0);
      kv[d + 36] = (_Float16)(b * c1 + a * s1);
    }
#pragma unroll
    for (int i = 0; i < 9; ++i) *(half8*)&Ls[tid * 120 + 8 * i] = *(half8*)&kv[8 * i];
#pragma unroll
    for (int i = 9; i < 13; ++i) *(half8*)&Ls[tid * 120 + 8 * i] = z;  // full 104: no holes
  }
  __syncthreads();
  {
    _Float16* dst = Ko + (size_t)t0 * KSTR;
#pragma unroll
    for (int it = 0; it < 13; ++it) {          // 256 rows x 13 chunks = 3328
      int j = tid + it * 256;
      int row = j / 13, c = j - row * 13;
      *(half8*)(dst + (size_t)j * 8) = *(const half8*)&Ls[row * 120 + c * 8];
    }
  }
}

// ---------- V pre-transpose -> Vt tiles [n,h,kb][d:80][76]; row d=72 = ones (l_s trick) ----------
__global__ __launch_bounds__(256) void transpose_v(const _Float16* __restrict__ QKV,
                                                   _Float16* __restrict__ Vt) {
  __shared__ __align__(16) _Float16 Vs[64 * 88];   // [key][d pad 88]
  const int tid = threadIdx.x;
  const int kb = blockIdx.x, h = blockIdx.y, n = blockIdx.z;
  const int s0 = n * SEGL + kb * 64;
  const _Float16* src = QKV + (size_t)s0 * 3456 + 2 * H_DIM + h * HD;
  for (int idx = tid; idx < 576; idx += 256) {
    int key = idx / 9, c = idx - key * 9;
    *(half8*)&Vs[key * 88 + c * 8] = *(const half8*)(src + (size_t)key * 3456 + c * 8);
  }
  __syncthreads();
  _Float16* dst = Vt + (((size_t)(n * NHEAD + h)) * 16 + kb) * VT_TILE;
  for (int idx = tid; idx < 800; idx += 256) {  // 80 rows x 10 chunks
    int d = idx / 10, c = idx - d * 10;
    if (c < 8) {            // key cols 0..63
      half8 v = {};
      if (d < HD) {
#pragma unroll
        for (int j = 0; j < 8; ++j) v[j] = Vs[(c * 8 + j) * 88 + d];
      } else if (d == HD) { // ones row: PV MFMA accumulates sum(P) here
#pragma unroll
        for (int j = 0; j < 8; ++j) v[j] = (_Float16)1.0f;
      }
      *(half8*)(dst + d * VSTR + c * 8) = v;
    } else if (c == 8) {
      *(half8*)(dst + d * VSTR + 64) = half8{};  // pad cols 64..71
    } else {
      *(half4*)(dst + d * VSTR + 72) = half4{};  // pad cols 72..75
    }
  }
}

// ---------- flash attention (S^T), 32 q/wave, 128 q/block, grid 1024 ----------
// r5 config exactly: launch_bounds(256,3) — (256,4) forced VGPR 80->64 and spilled (r7:
// WRITE_SIZE 140MB scratch, +24us total). Attn is latency/TLP-bound at 3 blocks/CU, no spill.
__global__ __launch_bounds__(256, 3) void attn_kernel(
    const _Float16* __restrict__ Qb, const _Float16* __restrict__ Kb,
    const _Float16* __restrict__ Vtb, _Float16* __restrict__ Ctx) {
  __shared__ __align__(16) _Float16 Kt[64 * KSTR];     // 13312 B
  __shared__ __align__(16) _Float16 Vt[80 * VSTR];     // 12160 B
  __shared__ __align__(16) _Float16 Ps[4 * 16 * PSTR]; //  9728 B  (16 q rows per wave)
  const int tid = threadIdx.x;
  const int lane = tid & 63, w = tid >> 6;
  const int quad = lane >> 4, l16 = lane & 15;
  // swizzle: 8 qb-blocks of one (h,n) share id mod 8 -> same XCD L2
  const int id = blockIdx.x;
  const int hn = id & 127, qb = id >> 7;
  const int h = hn >> 3, n = hn & 7;
  const size_t hseg = (size_t)(n * NHEAD + h);
  const _Float16* Qg = Qb + hseg * SEGL * QSTR;
  const _Float16* Kg = Kb + hseg * SEGL * KSTR;
  const _Float16* Vg = Vtb + hseg * 16 * VT_TILE;

  half8 qf[2][3];
#pragma unroll
  for (int qg = 0; qg < 2; ++qg) {
    int row = qb * 128 + w * 32 + qg * 16 + l16;
#pragma unroll
    for (int kc = 0; kc < 3; ++kc)
      qf[qg][kc] = *(const half8*)(Qg + (size_t)row * QSTR + kc * 32 + quad * 8);
  }
  floatx4 o_acc[2][5] = {};   // O^T[d = t*16+quad*4+r][q]; t=4,quad=2,r=0 carries sum(P)

  for (int kb = 0; kb < SEGL / 64; ++kb) {
    __syncthreads();
    // K tile: contiguous 13312 B
    {
      const char* base = (const char*)(Kg + (size_t)kb * 64 * KSTR);
#pragma unroll
      for (int i = 0; i < 3; ++i)
        gld_lds16(base + tid * 16 + i * 4096, (char*)Kt + tid * 16 + i * 4096);
      if (tid < 64)
        gld_lds16(base + 12288 + tid * 16, (char*)Kt + 12288 + tid * 16);
    }
    // V^T tile: contiguous 12160 B
    {
      const char* base = (const char*)(Vg + (size_t)kb * VT_TILE);
#pragma unroll
      for (int i = 0; i < 2; ++i)
        gld_lds16(base + tid * 16 + i * 4096, (char*)Vt + tid * 16 + i * 4096);
      if (tid < 248)
        gld_lds16(base + 8192 + tid * 16, (char*)Vt + 8192 + tid * 16);
    }
    __syncthreads();
    // S^T = K·Q^T (K-frags shared across both q-groups)
    floatx4 sa[2][4] = {};
    __builtin_amdgcn_s_setprio(1);
#pragma unroll
    for (int nt = 0; nt < 4; ++nt) {
      half8 kf[3];
#pragma unroll
      for (int kc = 0; kc < 3; ++kc)
        kf[kc] = *(const half8*)&Kt[(nt * 16 + l16) * KSTR + kc * 32 + quad * 8];
#pragma unroll
      for (int qg = 0; qg < 2; ++qg)
#pragma unroll
        for (int kc = 0; kc < 3; ++kc)
          sa[qg][nt] = __builtin_amdgcn_mfma_f32_16x16x32_f16(kf[kc], qf[qg][kc], sa[qg][nt], 0, 0, 0);
    }
    __builtin_amdgcn_s_setprio(0);
    // p = exp2(s), no max subtraction; no explicit sum (ones-row handles it)
#pragma unroll
    for (int qg = 0; qg < 2; ++qg)
#pragma unroll
      for (int nt = 0; nt < 4; ++nt)
#pragma unroll
        for (int r = 0; r < 4; ++r)
          sa[qg][nt][r] = exp2f(sa[qg][nt][r]);
    // V-frags once per tile, reused across both q-groups
    half8 vf[2][5];
#pragma unroll
    for (int kc2 = 0; kc2 < 2; ++kc2)
#pragma unroll
      for (int t = 0; t < 5; ++t)
        vf[kc2][t] = *(const half8*)&Vt[(t * 16 + l16) * VSTR + kc2 * 32 + quad * 8];
    // per q-group: P -> LDS (wave-private 16 rows, reused across qg; in-order DS = safe)
#pragma unroll
    for (int qg = 0; qg < 2; ++qg) {
      int prow = (w * 16 + l16) * PSTR;
#pragma unroll
      for (int nt = 0; nt < 4; ++nt) {
        half4 ph = { (_Float16)sa[qg][nt][0], (_Float16)sa[qg][nt][1],
                     (_Float16)sa[qg][nt][2], (_Float16)sa[qg][nt][3] };
        *(half4*)&Ps[prow + nt * 16 + quad * 4] = ph;
      }
      __builtin_amdgcn_s_setprio(1);
#pragma unroll
      for (int kc2 = 0; kc2 < 2; ++kc2) {
        half8 pb = *(const half8*)&Ps[(w * 16 + l16) * PSTR + kc2 * 32 + quad * 8];
#pragma unroll
        for (int t = 0; t < 5; ++t)
          o_acc[qg][t] = __builtin_amdgcn_mfma_f32_16x16x32_f16(vf[kc2][t], pb, o_acc[qg][t], 0, 0, 0);
      }
      __builtin_amdgcn_s_setprio(0);
    }
  }
  // epilogue: l = sum(P) lives at t=4, quad=2, r=0 -> broadcast from lane 32+l16
#pragma unroll
  for (int qg = 0; qg < 2; ++qg) {
    float lsum = __shfl(o_acc[qg][4][0], 32 + l16, 64);
    float rl = 1.0f / lsum;
    size_t s2 = (size_t)n * SEGL + qb * 128 + w * 32 + qg * 16 + l16;
#pragma unroll
    for (int t = 0; t < 5; ++t) {
      int d0 = t * 16 + quad * 4;
      if (d0 < HD) {
        half4 hv = { (_Float16)(o_acc[qg][t][0] * rl), (_Float16)(o_acc[qg][t][1] * rl),
                     (_Float16)(o_acc[qg][t][2] * rl), (_Float16)(o_acc[qg][t][3] * rl) };
        *(half4*)&Ctx[s2 * H_DIM + h * HD + d0] = hv;
      }
    }
  }
}

extern "C" void kernel_launch(void* const* d_in, const int* in_sizes, int n_in,
                              void* d_out, int out_size, void* d_ws, size_t ws_size,
                              hipStream_t stream) {
  const float* X    = (const float*)d_in[0];
  const float* cosb = (const float*)d_in[1];
  const float* sinb = (const float*)d_in[2];
  const float* Wqkv = (const float*)d_in[3];
  const float* bqkv = (const float*)d_in[4];
  const float* Wout = (const float*)d_in[5];
  const float* bout = (const float*)d_in[6];
  float* out = (float*)d_out;
  char* ws = (char*)d_ws;

  _Float16* Xb   = (_Float16*)(ws);              // 18,874,368 (reused as Ctx)
  _Float16* Wqt  = (_Float16*)(ws + 18874368);   //  7,962,624
  _Float16* Wot  = (_Float16*)(ws + 26836992);   //  2,654,208
  _Float16* QKVb = (_Float16*)(ws + 29491200);   // 56,623,104
  _Float16* Qb   = (_Float16*)(ws + 86114304);   // 25,165,824
  _Float16* Kb   = (_Float16*)(ws + 111280128);  // 27,262,976
  _Float16* Vtb  = (_Float16*)(ws + 138543104);  // 24,903,680
  _Float16* Ctx  = Xb;

  static bool attr_done = false;
  if (!attr_done) {
    hipFuncSetAttribute(reinterpret_cast<const void*>(gemm256<true>),
                        hipFuncAttributeMaxDynamicSharedMemorySize, 131072);
    attr_done = true;
  }

  cast_f32_f16<<<9216, 256, 0, stream>>>(X, Xb, S_TOT * H_DIM);
  transpose_cast<<<dim3(108, 36), dim3(32, 8), 0, stream>>>(Wqkv, Wqt, H_DIM, 3 * H_DIM);
  transpose_cast<<<dim3(36, 36), dim3(32, 8), 0, stream>>>(Wout, Wot, H_DIM, H_DIM);
  // QKV: M=8192, N=3456 (14 tiles, last masked), K=1152 -> 448 wg
  gemm256<true><<<448, 512, 131072, stream>>>(Xb, Wqt, bqkv, nullptr, QKVb,
                                              S_TOT, 3 * H_DIM, H_DIM, 14);
  rope_scatter<<<512, 256, 0, stream>>>(QKVb, cosb, sinb, Qb, Kb);
  transpose_v<<<dim3(16, 16, 8), 256, 0, stream>>>(QKVb, Vtb);
  attn_kernel<<<1024, 256, 0, stream>>>(Qb, Kb, Vtb, Ctx);
  // out: M=8192, N=1152, K=1152 -> 128^2 tiles, 576 wg (wave-balanced, 2.25 rounds)
  gemm_bt<false><<<576, 256, 0, stream>>>(Ctx, Wot, bout, out, nullptr,
                                          S_TOT, H_DIM, H_DIM, 9);
}